// Round 1
// baseline (2883.490 us; speedup 1.0000x reference)
//
#include <hip/hip_runtime.h>
#include <hip/hip_bf16.h>
#include <math.h>

#define D 128
#define ROWS_PER_BLOCK 16

// support[r][j] = sum_k x[r][k] * W[k][j]
// Block: 128 threads (thread j = output column), 16 rows per block.
// x rows staged in LDS; W read coalesced from global (64 KB, L2-resident).
__global__ void gcn_gemm_kernel(const float* __restrict__ x,
                                const float* __restrict__ W,
                                float* __restrict__ support,
                                int n_nodes) {
    __shared__ float xs[ROWS_PER_BLOCK][D];
    const int block_row = blockIdx.x * ROWS_PER_BLOCK;
    const int j = threadIdx.x;  // 0..127

    // Stage 16 rows of x into LDS (each thread loads one column of each row).
#pragma unroll
    for (int r = 0; r < ROWS_PER_BLOCK; ++r) {
        int row = block_row + r;
        xs[r][j] = (row < n_nodes) ? x[(size_t)row * D + j] : 0.0f;
    }
    __syncthreads();

    float acc[ROWS_PER_BLOCK];
#pragma unroll
    for (int r = 0; r < ROWS_PER_BLOCK; ++r) acc[r] = 0.0f;

    // k-loop unrolled by 4: W rows coalesced across threads, x via ds_read_b128.
    for (int k = 0; k < D; k += 4) {
        const float w0 = W[(k + 0) * D + j];
        const float w1 = W[(k + 1) * D + j];
        const float w2 = W[(k + 2) * D + j];
        const float w3 = W[(k + 3) * D + j];
#pragma unroll
        for (int r = 0; r < ROWS_PER_BLOCK; ++r) {
            const float4 xv = *reinterpret_cast<const float4*>(&xs[r][k]);
            acc[r] += xv.x * w0 + xv.y * w1 + xv.z * w2 + xv.w * w3;
        }
    }

#pragma unroll
    for (int r = 0; r < ROWS_PER_BLOCK; ++r) {
        int row = block_row + r;
        if (row < n_nodes) support[(size_t)row * D + j] = acc[r];
    }
}

// COO scatter: out[row[e]] += val[e] * support[col[e]]
// 32 threads per edge, each thread handles 4 contiguous features (float4 gather,
// 4 scalar fp32 atomics).
__global__ void gcn_scatter_kernel(const float* __restrict__ support,
                                   const int* __restrict__ erow,
                                   const int* __restrict__ ecol,
                                   const float* __restrict__ eval,
                                   float* __restrict__ out,
                                   int n_edges) {
    const long long tid = (long long)blockIdx.x * blockDim.x + threadIdx.x;
    const int edge = (int)(tid >> 5);
    if (edge >= n_edges) return;
    const int d4 = (int)(tid & 31) << 2;  // 0,4,...,124

    const int r = erow[edge];
    const int c = ecol[edge];
    const float v = eval[edge];

    const float4 s = *reinterpret_cast<const float4*>(&support[(size_t)c * D + d4]);
    float* o = &out[(size_t)r * D + d4];
    atomicAdd(o + 0, s.x * v);
    atomicAdd(o + 1, s.y * v);
    atomicAdd(o + 2, s.z * v);
    atomicAdd(o + 3, s.w * v);
}

__global__ void gcn_tanh_kernel(float* __restrict__ out, int n) {
    const int i = (blockIdx.x * blockDim.x + threadIdx.x) * 4;
    if (i < n) {
        float4 v = *reinterpret_cast<float4*>(&out[i]);
        v.x = tanhf(v.x);
        v.y = tanhf(v.y);
        v.z = tanhf(v.z);
        v.w = tanhf(v.w);
        *reinterpret_cast<float4*>(&out[i]) = v;
    }
}

extern "C" void kernel_launch(void* const* d_in, const int* in_sizes, int n_in,
                              void* d_out, int out_size, void* d_ws, size_t ws_size,
                              hipStream_t stream) {
    const float* x    = (const float*)d_in[0];
    const float* W    = (const float*)d_in[1];
    const int*   erow = (const int*)d_in[2];
    const int*   ecol = (const int*)d_in[3];
    const float* eval = (const float*)d_in[4];
    float* out = (float*)d_out;

    const int n_nodes = in_sizes[0] / D;   // 100000
    const int n_edges = in_sizes[2];       // 1600000

    float* support = (float*)d_ws;         // n_nodes * D floats = 51.2 MB

    // Zero the accumulator (d_out is poisoned 0xAA before every launch).
    hipMemsetAsync(d_out, 0, (size_t)out_size * sizeof(float), stream);

    // 1) support = x @ W
    {
        const int blocks = (n_nodes + ROWS_PER_BLOCK - 1) / ROWS_PER_BLOCK;
        gcn_gemm_kernel<<<blocks, D, 0, stream>>>(x, W, support, n_nodes);
    }

    // 2) out += scatter(v * support[col]) into row
    {
        const long long total = (long long)n_edges * 32;
        const int blocks = (int)((total + 255) / 256);
        gcn_scatter_kernel<<<blocks, 256, 0, stream>>>(support, erow, ecol, eval,
                                                       out, n_edges);
    }

    // 3) out = tanh(out), in place
    {
        const int vec = out_size / 4;
        const int blocks = (vec + 255) / 256;
        gcn_tanh_kernel<<<blocks, 256, 0, stream>>>(out, out_size);
    }
}

// Round 2
// 749.197 us; speedup vs baseline: 3.8488x; 3.8488x over previous
//
#include <hip/hip_runtime.h>
#include <hip/hip_bf16.h>
#include <math.h>

#define D 128
#define ROWS_PER_BLOCK 16

// ---------------- GEMM: support = x @ W ----------------
__global__ void gcn_gemm_kernel(const float* __restrict__ x,
                                const float* __restrict__ W,
                                float* __restrict__ support,
                                int n_nodes) {
    __shared__ float xs[ROWS_PER_BLOCK][D];
    const int block_row = blockIdx.x * ROWS_PER_BLOCK;
    const int j = threadIdx.x;  // 0..127

#pragma unroll
    for (int r = 0; r < ROWS_PER_BLOCK; ++r) {
        int row = block_row + r;
        xs[r][j] = (row < n_nodes) ? x[(size_t)row * D + j] : 0.0f;
    }
    __syncthreads();

    float acc[ROWS_PER_BLOCK];
#pragma unroll
    for (int r = 0; r < ROWS_PER_BLOCK; ++r) acc[r] = 0.0f;

    for (int k = 0; k < D; k += 4) {
        const float w0 = W[(k + 0) * D + j];
        const float w1 = W[(k + 1) * D + j];
        const float w2 = W[(k + 2) * D + j];
        const float w3 = W[(k + 3) * D + j];
#pragma unroll
        for (int r = 0; r < ROWS_PER_BLOCK; ++r) {
            const float4 xv = *reinterpret_cast<const float4*>(&xs[r][k]);
            acc[r] += xv.x * w0 + xv.y * w1 + xv.z * w2 + xv.w * w3;
        }
    }

#pragma unroll
    for (int r = 0; r < ROWS_PER_BLOCK; ++r) {
        int row = block_row + r;
        if (row < n_nodes) support[(size_t)row * D + j] = acc[r];
    }
}

// ---------------- CSR build ----------------
__global__ void gcn_hist_kernel(const int* __restrict__ erow,
                                int* __restrict__ counts, int n_edges) {
    const int e = blockIdx.x * blockDim.x + threadIdx.x;
    if (e < n_edges) atomicAdd(&counts[erow[e]], 1);
}

// Single-block chunked exclusive scan: counts[0..n) -> offsets[0..n], cursor copy.
__global__ void gcn_scan_kernel(const int* __restrict__ counts,
                                int* __restrict__ offsets,
                                int* __restrict__ cursor, int n) {
    __shared__ int partial[1024];
    const int tid = threadIdx.x;
    const int chunk = (n + 1023) / 1024;
    const int start = tid * chunk;
    const int end = min(start + chunk, n);

    int sum = 0;
    for (int i = start; i < end; ++i) sum += counts[i];
    partial[tid] = sum;
    __syncthreads();

    // Hillis-Steele inclusive scan over 1024 partials
    for (int off = 1; off < 1024; off <<= 1) {
        int t = (tid >= off) ? partial[tid - off] : 0;
        __syncthreads();
        partial[tid] += t;
        __syncthreads();
    }

    int run = (tid == 0) ? 0 : partial[tid - 1];  // exclusive base for this chunk
    for (int i = start; i < end; ++i) {
        offsets[i] = run;
        cursor[i] = run;
        run += counts[i];
    }
    if (tid == 1023) offsets[n] = partial[1023];
}

__global__ void gcn_bucket_kernel(const int* __restrict__ erow,
                                  const int* __restrict__ ecol,
                                  const float* __restrict__ eval,
                                  int* __restrict__ cursor,
                                  int* __restrict__ scol,
                                  float* __restrict__ sval, int n_edges) {
    const int e = blockIdx.x * blockDim.x + threadIdx.x;
    if (e >= n_edges) return;
    const int r = erow[e];
    const int pos = atomicAdd(&cursor[r], 1);
    scol[pos] = ecol[e];
    sval[pos] = eval[e];
}

// ---------------- per-node reduction + fused tanh ----------------
// 2 nodes per 256-thread block; 128 threads per node, thread j = feature j.
__global__ void gcn_gather_kernel(const float* __restrict__ support,
                                  const int* __restrict__ scol,
                                  const float* __restrict__ sval,
                                  const int* __restrict__ offsets,
                                  float* __restrict__ out, int n_nodes) {
    const int node = blockIdx.x * 2 + (threadIdx.x >> 7);
    const int j = threadIdx.x & 127;
    if (node >= n_nodes) return;

    const int beg = offsets[node];
    const int end = offsets[node + 1];

    float acc = 0.0f;
    int e = beg;
    for (; e + 1 < end; e += 2) {
        const int c0 = scol[e];
        const int c1 = scol[e + 1];
        const float v0 = sval[e];
        const float v1 = sval[e + 1];
        acc += v0 * support[(size_t)c0 * D + j];
        acc += v1 * support[(size_t)c1 * D + j];
    }
    if (e < end) acc += sval[e] * support[(size_t)scol[e] * D + j];

    out[(size_t)node * D + j] = tanhf(acc);
}

// ---------------- fallback (round-1 atomic path) ----------------
__global__ void gcn_scatter_kernel(const float* __restrict__ support,
                                   const int* __restrict__ erow,
                                   const int* __restrict__ ecol,
                                   const float* __restrict__ eval,
                                   float* __restrict__ out, int n_edges) {
    const long long tid = (long long)blockIdx.x * blockDim.x + threadIdx.x;
    const int edge = (int)(tid >> 5);
    if (edge >= n_edges) return;
    const int d4 = (int)(tid & 31) << 2;

    const int r = erow[edge];
    const int c = ecol[edge];
    const float v = eval[edge];

    const float4 s = *reinterpret_cast<const float4*>(&support[(size_t)c * D + d4]);
    float* o = &out[(size_t)r * D + d4];
    atomicAdd(o + 0, s.x * v);
    atomicAdd(o + 1, s.y * v);
    atomicAdd(o + 2, s.z * v);
    atomicAdd(o + 3, s.w * v);
}

__global__ void gcn_tanh_kernel(float* __restrict__ out, int n) {
    const int i = (blockIdx.x * blockDim.x + threadIdx.x) * 4;
    if (i < n) {
        float4 v = *reinterpret_cast<float4*>(&out[i]);
        v.x = tanhf(v.x);
        v.y = tanhf(v.y);
        v.z = tanhf(v.z);
        v.w = tanhf(v.w);
        *reinterpret_cast<float4*>(&out[i]) = v;
    }
}

extern "C" void kernel_launch(void* const* d_in, const int* in_sizes, int n_in,
                              void* d_out, int out_size, void* d_ws, size_t ws_size,
                              hipStream_t stream) {
    const float* x    = (const float*)d_in[0];
    const float* W    = (const float*)d_in[1];
    const int*   erow = (const int*)d_in[2];
    const int*   ecol = (const int*)d_in[3];
    const float* eval = (const float*)d_in[4];
    float* out = (float*)d_out;

    const int n_nodes = in_sizes[0] / D;   // 100000
    const int n_edges = in_sizes[2];       // 1600000

    // Workspace layout
    float* support = (float*)d_ws;                         // n_nodes*D floats
    int*   counts  = (int*)(support + (size_t)n_nodes * D); // n_nodes
    int*   offsets = counts + n_nodes;                      // n_nodes+1
    int*   cursor  = offsets + n_nodes + 1;                 // n_nodes
    int*   scol    = cursor + n_nodes;                      // n_edges
    float* sval    = (float*)(scol + n_edges);              // n_edges

    const size_t need = (size_t)n_nodes * D * sizeof(float)
                      + (size_t)(3 * n_nodes + 1) * sizeof(int)
                      + (size_t)n_edges * 2 * sizeof(int);

    // 1) support = x @ W
    {
        const int blocks = (n_nodes + ROWS_PER_BLOCK - 1) / ROWS_PER_BLOCK;
        gcn_gemm_kernel<<<blocks, D, 0, stream>>>(x, W, support, n_nodes);
    }

    if (ws_size >= need) {
        // 2) CSR build: histogram -> scan -> bucket
        hipMemsetAsync(counts, 0, (size_t)n_nodes * sizeof(int), stream);
        {
            const int blocks = (n_edges + 255) / 256;
            gcn_hist_kernel<<<blocks, 256, 0, stream>>>(erow, counts, n_edges);
        }
        gcn_scan_kernel<<<1, 1024, 0, stream>>>(counts, offsets, cursor, n_nodes);
        {
            const int blocks = (n_edges + 255) / 256;
            gcn_bucket_kernel<<<blocks, 256, 0, stream>>>(erow, ecol, eval, cursor,
                                                          scol, sval, n_edges);
        }
        // 3) per-node reduce + fused tanh (each node written exactly once)
        {
            const int blocks = (n_nodes + 1) / 2;
            gcn_gather_kernel<<<blocks, 256, 0, stream>>>(support, scol, sval,
                                                          offsets, out, n_nodes);
        }
    } else {
        // Fallback: atomic scatter path
        hipMemsetAsync(d_out, 0, (size_t)out_size * sizeof(float), stream);
        {
            const long long total = (long long)n_edges * 32;
            const int blocks = (int)((total + 255) / 256);
            gcn_scatter_kernel<<<blocks, 256, 0, stream>>>(support, erow, ecol, eval,
                                                           out, n_edges);
        }
        {
            const int vec = out_size / 4;
            const int blocks = (vec + 255) / 256;
            gcn_tanh_kernel<<<blocks, 256, 0, stream>>>(out, out_size);
        }
    }
}

// Round 3
// 492.843 us; speedup vs baseline: 5.8507x; 1.5202x over previous
//
#include <hip/hip_runtime.h>
#include <hip/hip_bf16.h>
#include <math.h>

#define D 128
#define ROWS_PER_BLOCK 16
#define SCAN_BLOCK 256

// ---------------- GEMM: support = x @ W ----------------
__global__ void gcn_gemm_kernel(const float* __restrict__ x,
                                const float* __restrict__ W,
                                float* __restrict__ support,
                                int n_nodes) {
    __shared__ float xs[ROWS_PER_BLOCK][D];
    const int block_row = blockIdx.x * ROWS_PER_BLOCK;
    const int j = threadIdx.x;  // 0..127

#pragma unroll
    for (int r = 0; r < ROWS_PER_BLOCK; ++r) {
        int row = block_row + r;
        xs[r][j] = (row < n_nodes) ? x[(size_t)row * D + j] : 0.0f;
    }
    __syncthreads();

    float acc[ROWS_PER_BLOCK];
#pragma unroll
    for (int r = 0; r < ROWS_PER_BLOCK; ++r) acc[r] = 0.0f;

    for (int k = 0; k < D; k += 4) {
        const float w0 = W[(k + 0) * D + j];
        const float w1 = W[(k + 1) * D + j];
        const float w2 = W[(k + 2) * D + j];
        const float w3 = W[(k + 3) * D + j];
#pragma unroll
        for (int r = 0; r < ROWS_PER_BLOCK; ++r) {
            const float4 xv = *reinterpret_cast<const float4*>(&xs[r][k]);
            acc[r] += xv.x * w0 + xv.y * w1 + xv.z * w2 + xv.w * w3;
        }
    }

#pragma unroll
    for (int r = 0; r < ROWS_PER_BLOCK; ++r) {
        int row = block_row + r;
        if (row < n_nodes) support[(size_t)row * D + j] = acc[r];
    }
}

// ---------------- CSR build ----------------
__global__ void gcn_hist_kernel(const int* __restrict__ erow,
                                int* __restrict__ counts, int n_edges) {
    const int e = blockIdx.x * blockDim.x + threadIdx.x;
    if (e < n_edges) atomicAdd(&counts[erow[e]], 1);
}

// Phase A: per-block exclusive scan of 256-element chunks; block totals out.
__global__ void gcn_scanA_kernel(const int* __restrict__ counts,
                                 int* __restrict__ offsets,
                                 int* __restrict__ bsums, int n) {
    __shared__ int sm[SCAN_BLOCK];
    const int tid = threadIdx.x;
    const int i = blockIdx.x * SCAN_BLOCK + tid;
    const int v = (i < n) ? counts[i] : 0;
    sm[tid] = v;
    __syncthreads();
    for (int off = 1; off < SCAN_BLOCK; off <<= 1) {
        int t = (tid >= off) ? sm[tid - off] : 0;
        __syncthreads();
        sm[tid] += t;
        __syncthreads();
    }
    if (i < n) offsets[i] = sm[tid] - v;  // exclusive within block
    if (tid == SCAN_BLOCK - 1) bsums[blockIdx.x] = sm[SCAN_BLOCK - 1];
}

// Phase B: single-block scan of block sums (nb <= 1024); writes total to offsets[n].
__global__ void gcn_scanB_kernel(const int* __restrict__ bsums,
                                 int* __restrict__ bbase,
                                 int* __restrict__ total_out, int nb) {
    __shared__ int sm[1024];
    const int tid = threadIdx.x;
    const int v = (tid < nb) ? bsums[tid] : 0;
    sm[tid] = v;
    __syncthreads();
    for (int off = 1; off < 1024; off <<= 1) {
        int t = (tid >= off) ? sm[tid - off] : 0;
        __syncthreads();
        sm[tid] += t;
        __syncthreads();
    }
    if (tid < nb) bbase[tid] = sm[tid] - v;
    if (tid == 1023) *total_out = sm[1023];
}

// Phase C: add block base; fill cursor.
__global__ void gcn_scanC_kernel(int* __restrict__ offsets,
                                 int* __restrict__ cursor,
                                 const int* __restrict__ bbase, int n) {
    const int i = blockIdx.x * SCAN_BLOCK + threadIdx.x;
    if (i < n) {
        const int o = offsets[i] + bbase[blockIdx.x];
        offsets[i] = o;
        cursor[i] = o;
    }
}

__global__ void gcn_bucket_kernel(const int* __restrict__ erow,
                                  const int* __restrict__ ecol,
                                  const float* __restrict__ eval,
                                  int* __restrict__ cursor,
                                  int* __restrict__ scol,
                                  float* __restrict__ sval, int n_edges) {
    const int e = blockIdx.x * blockDim.x + threadIdx.x;
    if (e >= n_edges) return;
    const int r = erow[e];
    const int pos = atomicAdd(&cursor[r], 1);
    scol[pos] = ecol[e];
    sval[pos] = eval[e];
}

// ---------------- per-node reduction + fused tanh ----------------
// 2 nodes per 256-thread block; 128 threads per node, thread j = feature j.
// Unrolled x4 so four independent 512B row-gathers are in flight.
__global__ void gcn_gather_kernel(const float* __restrict__ support,
                                  const int* __restrict__ scol,
                                  const float* __restrict__ sval,
                                  const int* __restrict__ offsets,
                                  float* __restrict__ out, int n_nodes) {
    const int node = blockIdx.x * 2 + (threadIdx.x >> 7);
    const int j = threadIdx.x & 127;
    if (node >= n_nodes) return;

    const int beg = offsets[node];
    const int end = offsets[node + 1];

    float acc0 = 0.0f, acc1 = 0.0f, acc2 = 0.0f, acc3 = 0.0f;
    int e = beg;
    for (; e + 3 < end; e += 4) {
        const int c0 = scol[e + 0];
        const int c1 = scol[e + 1];
        const int c2 = scol[e + 2];
        const int c3 = scol[e + 3];
        const float v0 = sval[e + 0];
        const float v1 = sval[e + 1];
        const float v2 = sval[e + 2];
        const float v3 = sval[e + 3];
        const float s0 = support[(size_t)c0 * D + j];
        const float s1 = support[(size_t)c1 * D + j];
        const float s2 = support[(size_t)c2 * D + j];
        const float s3 = support[(size_t)c3 * D + j];
        acc0 += v0 * s0;
        acc1 += v1 * s1;
        acc2 += v2 * s2;
        acc3 += v3 * s3;
    }
    for (; e < end; ++e) acc0 += sval[e] * support[(size_t)scol[e] * D + j];

    out[(size_t)node * D + j] = tanhf((acc0 + acc1) + (acc2 + acc3));
}

extern "C" void kernel_launch(void* const* d_in, const int* in_sizes, int n_in,
                              void* d_out, int out_size, void* d_ws, size_t ws_size,
                              hipStream_t stream) {
    const float* x    = (const float*)d_in[0];
    const float* W    = (const float*)d_in[1];
    const int*   erow = (const int*)d_in[2];
    const int*   ecol = (const int*)d_in[3];
    const float* eval = (const float*)d_in[4];
    float* out = (float*)d_out;

    const int n_nodes = in_sizes[0] / D;   // 100000
    const int n_edges = in_sizes[2];       // 1600000
    const int nb = (n_nodes + SCAN_BLOCK - 1) / SCAN_BLOCK;  // scan blocks (391)

    // Workspace layout
    float* support = (float*)d_ws;                          // n_nodes*D floats
    int*   counts  = (int*)(support + (size_t)n_nodes * D); // n_nodes
    int*   offsets = counts + n_nodes;                      // n_nodes+1
    int*   cursor  = offsets + n_nodes + 1;                 // n_nodes
    int*   bsums   = cursor + n_nodes;                      // nb
    int*   bbase   = bsums + nb;                            // nb
    int*   scol    = bbase + nb;                            // n_edges
    float* sval    = (float*)(scol + n_edges);              // n_edges

    // 1) support = x @ W
    {
        const int blocks = (n_nodes + ROWS_PER_BLOCK - 1) / ROWS_PER_BLOCK;
        gcn_gemm_kernel<<<blocks, D, 0, stream>>>(x, W, support, n_nodes);
    }

    // 2) CSR build: histogram -> 3-phase scan -> bucket
    hipMemsetAsync(counts, 0, (size_t)n_nodes * sizeof(int), stream);
    {
        const int blocks = (n_edges + 255) / 256;
        gcn_hist_kernel<<<blocks, 256, 0, stream>>>(erow, counts, n_edges);
    }
    gcn_scanA_kernel<<<nb, SCAN_BLOCK, 0, stream>>>(counts, offsets, bsums, n_nodes);
    gcn_scanB_kernel<<<1, 1024, 0, stream>>>(bsums, bbase, &offsets[n_nodes], nb);
    gcn_scanC_kernel<<<nb, SCAN_BLOCK, 0, stream>>>(offsets, cursor, bbase, n_nodes);
    {
        const int blocks = (n_edges + 255) / 256;
        gcn_bucket_kernel<<<blocks, 256, 0, stream>>>(erow, ecol, eval, cursor,
                                                      scol, sval, n_edges);
    }

    // 3) per-node reduce + fused tanh (each node written exactly once)
    {
        const int blocks = (n_nodes + 1) / 2;
        gcn_gather_kernel<<<blocks, 256, 0, stream>>>(support, scol, sval,
                                                      offsets, out, n_nodes);
    }
}

// Round 5
// 414.825 us; speedup vs baseline: 6.9511x; 1.1881x over previous
//
#include <hip/hip_runtime.h>
#include <hip/hip_bf16.h>
#include <hip/hip_fp16.h>
#include <math.h>

#define D 128
#define SCAN_BLOCK 256
#define GEMM_ROWS 32   // rows per block

// ---------------- GEMM: support_f16 = fp16(x @ W) ----------------
// 256 threads, 32 rows x 128 cols per block, 4x4 outputs per thread.
// W (64KB) + x-tile (16KB) staged in LDS; b128 LDS reads; compute-bound.
__global__ __launch_bounds__(256) void gcn_gemm_kernel(
        const float* __restrict__ x, const float* __restrict__ W,
        unsigned short* __restrict__ support2, int n_nodes) {
    __shared__ float ws[D][D];          // 64 KB
    __shared__ float xs[GEMM_ROWS][D];  // 16 KB
    const int tid = threadIdx.x;
    const int block_row = blockIdx.x * GEMM_ROWS;

    // Stage W: 16384 floats = 4096 float4, 16 passes of 256 threads.
    {
        const float4* Wv = (const float4*)W;
        float4* wsv = (float4*)&ws[0][0];
#pragma unroll
        for (int p = 0; p < 16; ++p) wsv[p * 256 + tid] = Wv[p * 256 + tid];
    }
    // Stage x tile: 4096 floats = 1024 float4, 4 passes.
    {
        float4* xsv = (float4*)&xs[0][0];
        const float4* xv = (const float4*)(x + (size_t)block_row * D);
        const int limit = (n_nodes - block_row) * (D / 4);  // float4s available
#pragma unroll
        for (int p = 0; p < 4; ++p) {
            const int i = p * 256 + tid;
            xsv[i] = (i < limit) ? xv[i] : make_float4(0.f, 0.f, 0.f, 0.f);
        }
    }
    __syncthreads();

    const int tx = tid & 31;   // col group: cols 4*tx..4*tx+3
    const int ty = tid >> 5;   // row group: rows 4*ty..4*ty+3

    float acc[4][4];
#pragma unroll
    for (int i = 0; i < 4; ++i)
#pragma unroll
        for (int j = 0; j < 4; ++j) acc[i][j] = 0.0f;

    for (int k = 0; k < D; k += 4) {
        float4 a[4], b[4];
#pragma unroll
        for (int i = 0; i < 4; ++i)
            a[i] = *reinterpret_cast<const float4*>(&xs[4 * ty + i][k]);
#pragma unroll
        for (int kk = 0; kk < 4; ++kk)
            b[kk] = *reinterpret_cast<const float4*>(&ws[k + kk][4 * tx]);
#pragma unroll
        for (int i = 0; i < 4; ++i) {
            acc[i][0] += a[i].x * b[0].x + a[i].y * b[1].x + a[i].z * b[2].x + a[i].w * b[3].x;
            acc[i][1] += a[i].x * b[0].y + a[i].y * b[1].y + a[i].z * b[2].y + a[i].w * b[3].y;
            acc[i][2] += a[i].x * b[0].z + a[i].y * b[1].z + a[i].z * b[2].z + a[i].w * b[3].z;
            acc[i][3] += a[i].x * b[0].w + a[i].y * b[1].w + a[i].z * b[2].w + a[i].w * b[3].w;
        }
    }

#pragma unroll
    for (int i = 0; i < 4; ++i) {
        const int row = block_row + 4 * ty + i;
        if (row < n_nodes) {
            const unsigned int lo =
                (unsigned int)__half_as_ushort(__float2half_rn(acc[i][0])) |
                ((unsigned int)__half_as_ushort(__float2half_rn(acc[i][1])) << 16);
            const unsigned int hi =
                (unsigned int)__half_as_ushort(__float2half_rn(acc[i][2])) |
                ((unsigned int)__half_as_ushort(__float2half_rn(acc[i][3])) << 16);
            uint2* dst = (uint2*)&support2[(size_t)row * D + 4 * tx];
            *dst = make_uint2(lo, hi);
        }
    }
}

// ---------------- CSR build ----------------
__global__ void gcn_hist_kernel(const int* __restrict__ erow,
                                int* __restrict__ counts, int n_edges) {
    const int e = blockIdx.x * blockDim.x + threadIdx.x;
    if (e < n_edges) atomicAdd(&counts[erow[e]], 1);
}

__global__ void gcn_scanA_kernel(const int* __restrict__ counts,
                                 int* __restrict__ offsets,
                                 int* __restrict__ bsums, int n) {
    __shared__ int sm[SCAN_BLOCK];
    const int tid = threadIdx.x;
    const int i = blockIdx.x * SCAN_BLOCK + tid;
    const int v = (i < n) ? counts[i] : 0;
    sm[tid] = v;
    __syncthreads();
    for (int off = 1; off < SCAN_BLOCK; off <<= 1) {
        int t = (tid >= off) ? sm[tid - off] : 0;
        __syncthreads();
        sm[tid] += t;
        __syncthreads();
    }
    if (i < n) offsets[i] = sm[tid] - v;
    if (tid == SCAN_BLOCK - 1) bsums[blockIdx.x] = sm[SCAN_BLOCK - 1];
}

__global__ void gcn_scanB_kernel(const int* __restrict__ bsums,
                                 int* __restrict__ bbase,
                                 int* __restrict__ total_out, int nb) {
    __shared__ int sm[1024];
    const int tid = threadIdx.x;
    const int v = (tid < nb) ? bsums[tid] : 0;
    sm[tid] = v;
    __syncthreads();
    for (int off = 1; off < 1024; off <<= 1) {
        int t = (tid >= off) ? sm[tid - off] : 0;
        __syncthreads();
        sm[tid] += t;
        __syncthreads();
    }
    if (tid < nb) bbase[tid] = sm[tid] - v;
    if (tid == 1023) *total_out = sm[1023];
}

__global__ void gcn_scanC_kernel(int* __restrict__ offsets,
                                 int* __restrict__ cursor,
                                 const int* __restrict__ bbase, int n) {
    const int i = blockIdx.x * SCAN_BLOCK + threadIdx.x;
    if (i < n) {
        const int o = offsets[i] + bbase[blockIdx.x];
        offsets[i] = o;
        cursor[i] = o;
    }
}

// Bucket: one 8B packed (col,val) write per edge.
__global__ void gcn_bucket_kernel(const int* __restrict__ erow,
                                  const int* __restrict__ ecol,
                                  const float* __restrict__ eval,
                                  int* __restrict__ cursor,
                                  int2* __restrict__ epack, int n_edges) {
    const int e = blockIdx.x * blockDim.x + threadIdx.x;
    if (e >= n_edges) return;
    const int r = erow[e];
    const int pos = atomicAdd(&cursor[r], 1);
    epack[pos] = make_int2(ecol[e], __float_as_int(eval[e]));
}

// ---------------- per-node reduction + fused tanh ----------------
// One wave per node (4 nodes per 256-thread block). Lane l owns features
// 2l, 2l+1 (one dword = 2 fp16). Edge records are wave-uniform scalar loads.
__global__ __launch_bounds__(256) void gcn_gather_kernel(
        const unsigned int* __restrict__ support_u,  // fp16x2 per dword
        const int2* __restrict__ epack,
        const int* __restrict__ offsets,
        float* __restrict__ out, int n_nodes) {
    const int node = __builtin_amdgcn_readfirstlane(
        blockIdx.x * 4 + (threadIdx.x >> 6));
    const int lane = threadIdx.x & 63;
    if (node >= n_nodes) return;

    const int beg = offsets[node];
    const int end = offsets[node + 1];

    float ax = 0.f, ay = 0.f, bx = 0.f, by = 0.f;
    int e = beg;
    for (; e + 3 < end; e += 4) {
        const int2 p0 = epack[e + 0];
        const int2 p1 = epack[e + 1];
        const int2 p2 = epack[e + 2];
        const int2 p3 = epack[e + 3];
        const unsigned int s0 = support_u[(size_t)p0.x * 64 + lane];
        const unsigned int s1 = support_u[(size_t)p1.x * 64 + lane];
        const unsigned int s2 = support_u[(size_t)p2.x * 64 + lane];
        const unsigned int s3 = support_u[(size_t)p3.x * 64 + lane];
        const float v0 = __int_as_float(p0.y);
        const float v1 = __int_as_float(p1.y);
        const float v2 = __int_as_float(p2.y);
        const float v3 = __int_as_float(p3.y);
        ax += v0 * __half2float(__ushort_as_half((unsigned short)(s0 & 0xFFFFu)));
        ay += v0 * __half2float(__ushort_as_half((unsigned short)(s0 >> 16)));
        bx += v1 * __half2float(__ushort_as_half((unsigned short)(s1 & 0xFFFFu)));
        by += v1 * __half2float(__ushort_as_half((unsigned short)(s1 >> 16)));
        ax += v2 * __half2float(__ushort_as_half((unsigned short)(s2 & 0xFFFFu)));
        ay += v2 * __half2float(__ushort_as_half((unsigned short)(s2 >> 16)));
        bx += v3 * __half2float(__ushort_as_half((unsigned short)(s3 & 0xFFFFu)));
        by += v3 * __half2float(__ushort_as_half((unsigned short)(s3 >> 16)));
    }
    for (; e < end; ++e) {
        const int2 p = epack[e];
        const unsigned int s = support_u[(size_t)p.x * 64 + lane];
        const float v = __int_as_float(p.y);
        ax += v * __half2float(__ushort_as_half((unsigned short)(s & 0xFFFFu)));
        ay += v * __half2float(__ushort_as_half((unsigned short)(s >> 16)));
    }

    float2* out2 = (float2*)out;
    out2[(size_t)node * 64 + lane] = make_float2(tanhf(ax + bx), tanhf(ay + by));
}

extern "C" void kernel_launch(void* const* d_in, const int* in_sizes, int n_in,
                              void* d_out, int out_size, void* d_ws, size_t ws_size,
                              hipStream_t stream) {
    const float* x    = (const float*)d_in[0];
    const float* W    = (const float*)d_in[1];
    const int*   erow = (const int*)d_in[2];
    const int*   ecol = (const int*)d_in[3];
    const float* eval = (const float*)d_in[4];
    float* out = (float*)d_out;

    const int n_nodes = in_sizes[0] / D;   // 100000
    const int n_edges = in_sizes[2];       // 1600000
    const int nb = (n_nodes + SCAN_BLOCK - 1) / SCAN_BLOCK;  // 391

    // Workspace layout (8B-aligned pieces)
    unsigned short* support2 = (unsigned short*)d_ws;        // n_nodes*D fp16
    int2* epack   = (int2*)(support2 + (size_t)n_nodes * D); // n_edges int2
    int*  counts  = (int*)(epack + n_edges);                 // n_nodes
    int*  offsets = counts + n_nodes;                        // n_nodes+1
    int*  cursor  = offsets + n_nodes + 1;                   // n_nodes
    int*  bsums   = cursor + n_nodes;                        // nb
    int*  bbase   = bsums + nb;                              // nb

    // 1) support = fp16(x @ W)
    gcn_gemm_kernel<<<(n_nodes + GEMM_ROWS - 1) / GEMM_ROWS, 256, 0, stream>>>(
        x, W, support2, n_nodes);

    // 2) CSR build
    hipMemsetAsync(counts, 0, (size_t)n_nodes * sizeof(int), stream);
    gcn_hist_kernel<<<(n_edges + 255) / 256, 256, 0, stream>>>(erow, counts, n_edges);
    gcn_scanA_kernel<<<nb, SCAN_BLOCK, 0, stream>>>(counts, offsets, bsums, n_nodes);
    gcn_scanB_kernel<<<1, 1024, 0, stream>>>(bsums, bbase, &offsets[n_nodes], nb);
    gcn_scanC_kernel<<<nb, SCAN_BLOCK, 0, stream>>>(offsets, cursor, bbase, n_nodes);
    gcn_bucket_kernel<<<(n_edges + 255) / 256, 256, 0, stream>>>(
        erow, ecol, eval, cursor, epack, n_edges);

    // 3) per-node reduce + fused tanh
    gcn_gather_kernel<<<(n_nodes + 3) / 4, 256, 0, stream>>>(
        (const unsigned int*)support2, epack, offsets, out, n_nodes);
}

// Round 6
// 343.609 us; speedup vs baseline: 8.3918x; 1.2073x over previous
//
#include <hip/hip_runtime.h>
#include <hip/hip_bf16.h>
#include <hip/hip_fp16.h>
#include <math.h>

#define D 128
#define SCAN_BLOCK 256
#define GEMM_ROWS 32     // rows per GEMM block
#define BIN_SHIFT 9      // 512 rows per coarse bin
#define BIN_ROWS 512
#define NB_MAX 256       // >= nbins (196 for 100k nodes)
#define CPAD 16          // ints; one 64B line per coarse cursor
#define AW 8192          // edges per stage-A block window

// ---------------- GEMM: support_f16 = fp16(x @ W) ----------------
__global__ __launch_bounds__(256) void gcn_gemm_kernel(
        const float* __restrict__ x, const float* __restrict__ W,
        unsigned short* __restrict__ support2, int n_nodes) {
    __shared__ float ws[D][D];          // 64 KB
    __shared__ float xs[GEMM_ROWS][D];  // 16 KB
    const int tid = threadIdx.x;
    const int block_row = blockIdx.x * GEMM_ROWS;

    {
        const float4* Wv = (const float4*)W;
        float4* wsv = (float4*)&ws[0][0];
#pragma unroll
        for (int p = 0; p < 16; ++p) wsv[p * 256 + tid] = Wv[p * 256 + tid];
    }
    {
        float4* xsv = (float4*)&xs[0][0];
        const float4* xv = (const float4*)(x + (size_t)block_row * D);
        const int limit = (n_nodes - block_row) * (D / 4);
#pragma unroll
        for (int p = 0; p < 4; ++p) {
            const int i = p * 256 + tid;
            xsv[i] = (i < limit) ? xv[i] : make_float4(0.f, 0.f, 0.f, 0.f);
        }
    }
    __syncthreads();

    const int tx = tid & 31;   // cols 4*tx..4*tx+3
    const int ty = tid >> 5;   // rows 4*ty..4*ty+3

    float acc[4][4];
#pragma unroll
    for (int i = 0; i < 4; ++i)
#pragma unroll
        for (int j = 0; j < 4; ++j) acc[i][j] = 0.0f;

    for (int k = 0; k < D; k += 4) {
        float4 a[4], b[4];
#pragma unroll
        for (int i = 0; i < 4; ++i)
            a[i] = *reinterpret_cast<const float4*>(&xs[4 * ty + i][k]);
#pragma unroll
        for (int kk = 0; kk < 4; ++kk)
            b[kk] = *reinterpret_cast<const float4*>(&ws[k + kk][4 * tx]);
#pragma unroll
        for (int i = 0; i < 4; ++i) {
            acc[i][0] += a[i].x * b[0].x + a[i].y * b[1].x + a[i].z * b[2].x + a[i].w * b[3].x;
            acc[i][1] += a[i].x * b[0].y + a[i].y * b[1].y + a[i].z * b[2].y + a[i].w * b[3].y;
            acc[i][2] += a[i].x * b[0].z + a[i].y * b[1].z + a[i].z * b[2].z + a[i].w * b[3].z;
            acc[i][3] += a[i].x * b[0].w + a[i].y * b[1].w + a[i].z * b[2].w + a[i].w * b[3].w;
        }
    }

#pragma unroll
    for (int i = 0; i < 4; ++i) {
        const int row = block_row + 4 * ty + i;
        if (row < n_nodes) {
            const unsigned int lo =
                (unsigned int)__half_as_ushort(__float2half_rn(acc[i][0])) |
                ((unsigned int)__half_as_ushort(__float2half_rn(acc[i][1])) << 16);
            const unsigned int hi =
                (unsigned int)__half_as_ushort(__float2half_rn(acc[i][2])) |
                ((unsigned int)__half_as_ushort(__float2half_rn(acc[i][3])) << 16);
            uint2* dst = (uint2*)&support2[(size_t)row * D + 4 * tx];
            *dst = make_uint2(lo, hi);
        }
    }
}

// ---------------- per-row histogram + scan ----------------
__global__ void gcn_hist_kernel(const int* __restrict__ erow,
                                int* __restrict__ counts, int n_edges) {
    const int e = blockIdx.x * blockDim.x + threadIdx.x;
    if (e < n_edges) atomicAdd(&counts[erow[e]], 1);
}

__global__ void gcn_scanA_kernel(const int* __restrict__ counts,
                                 int* __restrict__ offsets,
                                 int* __restrict__ bsums, int n) {
    __shared__ int sm[SCAN_BLOCK];
    const int tid = threadIdx.x;
    const int i = blockIdx.x * SCAN_BLOCK + tid;
    const int v = (i < n) ? counts[i] : 0;
    sm[tid] = v;
    __syncthreads();
    for (int off = 1; off < SCAN_BLOCK; off <<= 1) {
        int t = (tid >= off) ? sm[tid - off] : 0;
        __syncthreads();
        sm[tid] += t;
        __syncthreads();
    }
    if (i < n) offsets[i] = sm[tid] - v;
    if (tid == SCAN_BLOCK - 1) bsums[blockIdx.x] = sm[SCAN_BLOCK - 1];
}

__global__ void gcn_scanB_kernel(const int* __restrict__ bsums,
                                 int* __restrict__ bbase,
                                 int* __restrict__ total_out, int nb) {
    __shared__ int sm[1024];
    const int tid = threadIdx.x;
    const int v = (tid < nb) ? bsums[tid] : 0;
    sm[tid] = v;
    __syncthreads();
    for (int off = 1; off < 1024; off <<= 1) {
        int t = (tid >= off) ? sm[tid - off] : 0;
        __syncthreads();
        sm[tid] += t;
        __syncthreads();
    }
    if (tid < nb) bbase[tid] = sm[tid] - v;
    if (tid == 1023) *total_out = sm[1023];
}

__global__ void gcn_scanC_kernel(int* __restrict__ offsets,
                                 const int* __restrict__ bbase, int n) {
    const int i = blockIdx.x * SCAN_BLOCK + threadIdx.x;
    if (i < n) offsets[i] += bbase[blockIdx.x];
}

// Init coarse-bin cursors (one padded line per bin) from row offsets.
__global__ void gcn_ccur_init_kernel(const int* __restrict__ offsets,
                                     int* __restrict__ ccur, int nbins) {
    const int b = blockIdx.x * blockDim.x + threadIdx.x;
    if (b < nbins) ccur[b * CPAD] = offsets[b << BIN_SHIFT];
}

// ---------------- Stage A: block-local counting sort into coarse bins ----
// Each block: 8192 edges -> LDS hist over nbins -> claim global chunk per bin
// -> LDS-sorted records -> contiguous per-bin group writes (~line-merged).
// Record: x = (row<<15)|fp16(val) [sign 0], y = col.
__global__ __launch_bounds__(256) void gcn_binA_kernel(
        const int* __restrict__ erow, const int* __restrict__ ecol,
        const float* __restrict__ eval, int* __restrict__ ccur,
        uint2* __restrict__ tmp8, int n_edges, int nbins) {
    __shared__ uint2 recs[AW];      // 64 KB
    __shared__ int hist[NB_MAX];    // counts, then running local cursor
    __shared__ int lstart[NB_MAX];  // local exclusive starts
    __shared__ int gbase[NB_MAX];   // scan scratch, then global chunk base
    const int t = threadIdx.x;
    const int w0 = blockIdx.x * AW;
    const int wend = min(w0 + AW, n_edges);
    const int cnt = wend - w0;

    for (int i = t; i < NB_MAX; i += 256) hist[i] = 0;
    __syncthreads();

    // Pass 1: histogram by coarse bin.
    for (int i = w0 + t; i < wend; i += 256)
        atomicAdd(&hist[erow[i] >> BIN_SHIFT], 1);
    __syncthreads();

    // Block-local exclusive scan of hist (256 slots, Hillis-Steele).
    {
        const int v = hist[t];
        gbase[t] = v;
        __syncthreads();
        for (int off = 1; off < 256; off <<= 1) {
            int tv = (t >= off) ? gbase[t - off] : 0;
            __syncthreads();
            gbase[t] += tv;
            __syncthreads();
        }
        lstart[t] = gbase[t] - v;
        __syncthreads();
    }

    // Claim global chunk per non-empty bin; repurpose hist as local cursor.
    {
        const int c = hist[t];
        int gb = 0;
        if (t < nbins && c > 0) gb = atomicAdd(&ccur[t * CPAD], c);
        __syncthreads();
        gbase[t] = gb;
        hist[t] = lstart[t];
    }
    __syncthreads();

    // Pass 2: re-read edges (L2-hot), place into LDS sorted by bin.
    for (int i = w0 + t; i < wend; i += 256) {
        const int r = erow[i];
        const int c = ecol[i];
        const unsigned short vh = __half_as_ushort(__float2half_rn(eval[i]));
        const int b = r >> BIN_SHIFT;
        const int p = atomicAdd(&hist[b], 1);
        recs[p] = make_uint2(((unsigned)r << 15) | vh, (unsigned)c);
    }
    __syncthreads();

    // Pass 3: write out; consecutive s within a bin-group -> contiguous global.
    for (int s = t; s < cnt; s += 256) {
        const uint2 rec = recs[s];
        const int b = (int)(rec.x >> 15) >> BIN_SHIFT;
        tmp8[gbase[b] + (s - lstart[b])] = rec;
    }
}

// ---------------- Stage B: exact CSR placement within a bin ----------------
// One block per bin; writes confined to a block-exclusive region -> merged.
// Final record: (col<<15) | fp16(val).
__global__ __launch_bounds__(256) void gcn_binB_kernel(
        const uint2* __restrict__ tmp8, const int* __restrict__ offsets,
        unsigned int* __restrict__ rec4, int n_nodes) {
    __shared__ int cur[BIN_ROWS];
    const int bin = blockIdx.x;
    const int r0 = bin << BIN_SHIFT;
    const int t = threadIdx.x;
    for (int i = t; i < BIN_ROWS; i += 256) {
        const int row = r0 + i;
        cur[i] = (row < n_nodes) ? offsets[row] : 0;
    }
    __syncthreads();
    const int beg = offsets[r0];
    const int end = offsets[min(r0 + BIN_ROWS, n_nodes)];
    for (int i = beg + t; i < end; i += 256) {
        const uint2 p = tmp8[i];
        const int r = (int)(p.x >> 15);
        const int pos = atomicAdd(&cur[r - r0], 1);
        rec4[pos] = (p.y << 15) | (p.x & 0x7FFFu);
    }
}

// ---------------- per-node reduction + fused tanh ----------------
// One wave per node; lane l owns features 2l, 2l+1 (one fp16x2 dword).
__global__ __launch_bounds__(256) void gcn_gather_kernel(
        const unsigned int* __restrict__ support_u,
        const unsigned int* __restrict__ rec4,
        const int* __restrict__ offsets,
        float* __restrict__ out, int n_nodes) {
    const int node = __builtin_amdgcn_readfirstlane(
        blockIdx.x * 4 + (threadIdx.x >> 6));
    const int lane = threadIdx.x & 63;
    if (node >= n_nodes) return;

    const int beg = offsets[node];
    const int end = offsets[node + 1];

    float ax = 0.f, ay = 0.f, bx = 0.f, by = 0.f;
    int e = beg;
    for (; e + 3 < end; e += 4) {
        const unsigned r0 = rec4[e + 0];
        const unsigned r1 = rec4[e + 1];
        const unsigned r2 = rec4[e + 2];
        const unsigned r3 = rec4[e + 3];
        const unsigned s0 = support_u[(size_t)(r0 >> 15) * 64 + lane];
        const unsigned s1 = support_u[(size_t)(r1 >> 15) * 64 + lane];
        const unsigned s2 = support_u[(size_t)(r2 >> 15) * 64 + lane];
        const unsigned s3 = support_u[(size_t)(r3 >> 15) * 64 + lane];
        const float v0 = __half2float(__ushort_as_half((unsigned short)(r0 & 0x7FFFu)));
        const float v1 = __half2float(__ushort_as_half((unsigned short)(r1 & 0x7FFFu)));
        const float v2 = __half2float(__ushort_as_half((unsigned short)(r2 & 0x7FFFu)));
        const float v3 = __half2float(__ushort_as_half((unsigned short)(r3 & 0x7FFFu)));
        ax += v0 * __half2float(__ushort_as_half((unsigned short)(s0 & 0xFFFFu)));
        ay += v0 * __half2float(__ushort_as_half((unsigned short)(s0 >> 16)));
        bx += v1 * __half2float(__ushort_as_half((unsigned short)(s1 & 0xFFFFu)));
        by += v1 * __half2float(__ushort_as_half((unsigned short)(s1 >> 16)));
        ax += v2 * __half2float(__ushort_as_half((unsigned short)(s2 & 0xFFFFu)));
        ay += v2 * __half2float(__ushort_as_half((unsigned short)(s2 >> 16)));
        bx += v3 * __half2float(__ushort_as_half((unsigned short)(s3 & 0xFFFFu)));
        by += v3 * __half2float(__ushort_as_half((unsigned short)(s3 >> 16)));
    }
    for (; e < end; ++e) {
        const unsigned r = rec4[e];
        const unsigned s = support_u[(size_t)(r >> 15) * 64 + lane];
        const float v = __half2float(__ushort_as_half((unsigned short)(r & 0x7FFFu)));
        ax += v * __half2float(__ushort_as_half((unsigned short)(s & 0xFFFFu)));
        ay += v * __half2float(__ushort_as_half((unsigned short)(s >> 16)));
    }

    float2* out2 = (float2*)out;
    out2[(size_t)node * 64 + lane] = make_float2(tanhf(ax + bx), tanhf(ay + by));
}

extern "C" void kernel_launch(void* const* d_in, const int* in_sizes, int n_in,
                              void* d_out, int out_size, void* d_ws, size_t ws_size,
                              hipStream_t stream) {
    const float* x    = (const float*)d_in[0];
    const float* W    = (const float*)d_in[1];
    const int*   erow = (const int*)d_in[2];
    const int*   ecol = (const int*)d_in[3];
    const float* eval = (const float*)d_in[4];
    float* out = (float*)d_out;

    const int n_nodes = in_sizes[0] / D;   // 100000
    const int n_edges = in_sizes[2];       // 1600000
    const int nb = (n_nodes + SCAN_BLOCK - 1) / SCAN_BLOCK;       // 391
    const int nbins = (n_nodes + BIN_ROWS - 1) >> BIN_SHIFT;      // 196

    // Workspace layout
    unsigned short* support2 = (unsigned short*)d_ws;             // 25.6 MB
    uint2* tmp8   = (uint2*)(support2 + (size_t)n_nodes * D);     // 12.8 MB
    unsigned int* rec4 = (unsigned int*)(tmp8 + n_edges);         // 6.4 MB
    int*  counts  = (int*)(rec4 + n_edges);                       // n_nodes
    int*  offsets = counts + n_nodes;                             // n_nodes+1
    int*  bsums   = offsets + n_nodes + 1;                        // nb
    int*  bbase   = bsums + nb;                                   // nb
    int*  ccur    = bbase + nb;                                   // nbins*CPAD

    // 1) support = fp16(x @ W)
    gcn_gemm_kernel<<<(n_nodes + GEMM_ROWS - 1) / GEMM_ROWS, 256, 0, stream>>>(
        x, W, support2, n_nodes);

    // 2) per-row offsets
    hipMemsetAsync(counts, 0, (size_t)n_nodes * sizeof(int), stream);
    gcn_hist_kernel<<<(n_edges + 255) / 256, 256, 0, stream>>>(erow, counts, n_edges);
    gcn_scanA_kernel<<<nb, SCAN_BLOCK, 0, stream>>>(counts, offsets, bsums, n_nodes);
    gcn_scanB_kernel<<<1, 1024, 0, stream>>>(bsums, bbase, &offsets[n_nodes], nb);
    gcn_scanC_kernel<<<nb, SCAN_BLOCK, 0, stream>>>(offsets, bbase, n_nodes);

    // 3) two-stage binned CSR build
    gcn_ccur_init_kernel<<<(nbins + 255) / 256, 256, 0, stream>>>(offsets, ccur, nbins);
    gcn_binA_kernel<<<(n_edges + AW - 1) / AW, 256, 0, stream>>>(
        erow, ecol, eval, ccur, tmp8, n_edges, nbins);
    gcn_binB_kernel<<<nbins, 256, 0, stream>>>(tmp8, offsets, rec4, n_nodes);

    // 4) per-node reduce + fused tanh
    gcn_gather_kernel<<<(n_nodes + 3) / 4, 256, 0, stream>>>(
        (const unsigned int*)support2, rec4, offsets, out, n_nodes);
}

// Round 7
// 315.713 us; speedup vs baseline: 9.1333x; 1.0884x over previous
//
#include <hip/hip_runtime.h>
#include <hip/hip_bf16.h>
#include <hip/hip_fp16.h>
#include <math.h>

#define D 128
#define SCAN_BLOCK 256
#define BIN_SHIFT 9      // 512 rows per coarse bin
#define BIN_ROWS 512
#define NB_MAX 256       // >= nbins (196 for 100k nodes)
#define CPAD 16          // ints; one 64B line per coarse cursor
#define AW 8192          // edges per stage-A block window

typedef _Float16 half8 __attribute__((ext_vector_type(8)));
typedef float floatx4 __attribute__((ext_vector_type(4)));

// ---------------- W transpose + fp16 convert: wt[n][k] = f16(W[k][n]) ------
__global__ void gcn_wt_kernel(const float* __restrict__ W,
                              unsigned short* __restrict__ wt) {
    const int i = blockIdx.x * 256 + threadIdx.x;  // i = n*128 + k
    const int n = i >> 7, k = i & 127;
    wt[i] = __half_as_ushort(__float2half_rn(W[k * D + n]));
}

// ---------------- GEMM: support_f16 = fp16(x @ W), f16 MFMA ----------------
// No LDS. Each wave: 32 rows x 128 cols. A-frags straight from fp32 x
// (converted in-register), B-frags from wt (L1/L2-hot half8 loads).
// MFMA 16x16x32_f16: A[m=lane&15][k=quad*8+j]; B[k=quad*8+j][n=lane&15];
// D: row=quad*4+reg, col=lane&15 (verified layouts).
__global__ __launch_bounds__(256) void gcn_gemm_kernel(
        const float* __restrict__ x, const unsigned short* __restrict__ wt,
        unsigned short* __restrict__ support2, int n_nodes) {
    const int wave = threadIdx.x >> 6;
    const int lane = threadIdx.x & 63;
    const int q = lane >> 4;      // 0..3
    const int n16 = lane & 15;    // 0..15
    const int row_base = blockIdx.x * 128 + wave * 32;  // 32 rows per wave
    if (row_base >= n_nodes) return;   // 32 | 100000, no partial waves

    const half8* wt8 = (const half8*)wt;  // 16 B = 8 halves; wt row = 16 half8

    floatx4 acc[2][8];
#pragma unroll
    for (int mt = 0; mt < 2; ++mt)
#pragma unroll
        for (int nt = 0; nt < 8; ++nt) acc[mt][nt] = (floatx4){0.f, 0.f, 0.f, 0.f};

#pragma unroll
    for (int kc = 0; kc < 4; ++kc) {
        half8 b[8];
#pragma unroll
        for (int nt = 0; nt < 8; ++nt)
            b[nt] = wt8[(nt * 16 + n16) * 16 + kc * 4 + q];
#pragma unroll
        for (int mt = 0; mt < 2; ++mt) {
            const float* xp = x + (size_t)(row_base + mt * 16 + n16) * D
                                + kc * 32 + q * 8;
            const float4 f0 = *(const float4*)xp;
            const float4 f1 = *(const float4*)(xp + 4);
            half8 a;
            a[0] = (_Float16)f0.x; a[1] = (_Float16)f0.y;
            a[2] = (_Float16)f0.z; a[3] = (_Float16)f0.w;
            a[4] = (_Float16)f1.x; a[5] = (_Float16)f1.y;
            a[6] = (_Float16)f1.z; a[7] = (_Float16)f1.w;
#pragma unroll
            for (int nt = 0; nt < 8; ++nt)
                acc[mt][nt] = __builtin_amdgcn_mfma_f32_16x16x32_f16(
                    a, b[nt], acc[mt][nt], 0, 0, 0);
        }
    }

    // Epilogue: D[row=quad*4+i][col=n16] per reg i -> fp16 stores.
#pragma unroll
    for (int mt = 0; mt < 2; ++mt) {
        const int r0 = row_base + mt * 16 + q * 4;
#pragma unroll
        for (int nt = 0; nt < 8; ++nt) {
            const int col = nt * 16 + n16;
#pragma unroll
            for (int i = 0; i < 4; ++i)
                support2[(size_t)(r0 + i) * D + col] =
                    __half_as_ushort(__float2half_rn(acc[mt][nt][i]));
        }
    }
}

// ---------------- per-row histogram + scan ----------------
__global__ void gcn_hist_kernel(const int* __restrict__ erow,
                                int* __restrict__ counts, int n_edges) {
    const int e = blockIdx.x * blockDim.x + threadIdx.x;
    if (e < n_edges) atomicAdd(&counts[erow[e]], 1);
}

__global__ void gcn_scanA_kernel(const int* __restrict__ counts,
                                 int* __restrict__ offsets,
                                 int* __restrict__ bsums, int n) {
    __shared__ int sm[SCAN_BLOCK];
    const int tid = threadIdx.x;
    const int i = blockIdx.x * SCAN_BLOCK + tid;
    const int v = (i < n) ? counts[i] : 0;
    sm[tid] = v;
    __syncthreads();
    for (int off = 1; off < SCAN_BLOCK; off <<= 1) {
        int t = (tid >= off) ? sm[tid - off] : 0;
        __syncthreads();
        sm[tid] += t;
        __syncthreads();
    }
    if (i < n) offsets[i] = sm[tid] - v;
    if (tid == SCAN_BLOCK - 1) bsums[blockIdx.x] = sm[SCAN_BLOCK - 1];
}

__global__ void gcn_scanB_kernel(const int* __restrict__ bsums,
                                 int* __restrict__ bbase,
                                 int* __restrict__ total_out, int nb) {
    __shared__ int sm[1024];
    const int tid = threadIdx.x;
    const int v = (tid < nb) ? bsums[tid] : 0;
    sm[tid] = v;
    __syncthreads();
    for (int off = 1; off < 1024; off <<= 1) {
        int t = (tid >= off) ? sm[tid - off] : 0;
        __syncthreads();
        sm[tid] += t;
        __syncthreads();
    }
    if (tid < nb) bbase[tid] = sm[tid] - v;
    if (tid == 1023) *total_out = sm[1023];
}

__global__ void gcn_scanC_kernel(int* __restrict__ offsets,
                                 const int* __restrict__ bbase, int n) {
    const int i = blockIdx.x * SCAN_BLOCK + threadIdx.x;
    if (i < n) offsets[i] += bbase[blockIdx.x];
}

// Init coarse-bin cursors (one padded line per bin) from row offsets.
__global__ void gcn_ccur_init_kernel(const int* __restrict__ offsets,
                                     int* __restrict__ ccur, int nbins) {
    const int b = blockIdx.x * blockDim.x + threadIdx.x;
    if (b < nbins) ccur[b * CPAD] = offsets[b << BIN_SHIFT];
}

// ---------------- Stage A: block-local counting sort into coarse bins ----
__global__ __launch_bounds__(256) void gcn_binA_kernel(
        const int* __restrict__ erow, const int* __restrict__ ecol,
        const float* __restrict__ eval, int* __restrict__ ccur,
        uint2* __restrict__ tmp8, int n_edges, int nbins) {
    __shared__ uint2 recs[AW];      // 64 KB
    __shared__ int hist[NB_MAX];
    __shared__ int lstart[NB_MAX];
    __shared__ int gbase[NB_MAX];
    const int t = threadIdx.x;
    const int w0 = blockIdx.x * AW;
    const int wend = min(w0 + AW, n_edges);
    const int cnt = wend - w0;

    for (int i = t; i < NB_MAX; i += 256) hist[i] = 0;
    __syncthreads();

    for (int i = w0 + t; i < wend; i += 256)
        atomicAdd(&hist[erow[i] >> BIN_SHIFT], 1);
    __syncthreads();

    {
        const int v = hist[t];
        gbase[t] = v;
        __syncthreads();
        for (int off = 1; off < 256; off <<= 1) {
            int tv = (t >= off) ? gbase[t - off] : 0;
            __syncthreads();
            gbase[t] += tv;
            __syncthreads();
        }
        lstart[t] = gbase[t] - v;
        __syncthreads();
    }

    {
        const int c = hist[t];
        int gb = 0;
        if (t < nbins && c > 0) gb = atomicAdd(&ccur[t * CPAD], c);
        __syncthreads();
        gbase[t] = gb;
        hist[t] = lstart[t];
    }
    __syncthreads();

    for (int i = w0 + t; i < wend; i += 256) {
        const int r = erow[i];
        const int c = ecol[i];
        const unsigned short vh = __half_as_ushort(__float2half_rn(eval[i]));
        const int b = r >> BIN_SHIFT;
        const int p = atomicAdd(&hist[b], 1);
        recs[p] = make_uint2(((unsigned)r << 15) | vh, (unsigned)c);
    }
    __syncthreads();

    for (int s = t; s < cnt; s += 256) {
        const uint2 rec = recs[s];
        const int b = (int)(rec.x >> 15) >> BIN_SHIFT;
        tmp8[gbase[b] + (s - lstart[b])] = rec;
    }
}

// ---------------- Stage B: exact CSR placement within a bin ----------------
__global__ __launch_bounds__(256) void gcn_binB_kernel(
        const uint2* __restrict__ tmp8, const int* __restrict__ offsets,
        unsigned int* __restrict__ rec4, int n_nodes) {
    __shared__ int cur[BIN_ROWS];
    const int bin = blockIdx.x;
    const int r0 = bin << BIN_SHIFT;
    const int t = threadIdx.x;
    for (int i = t; i < BIN_ROWS; i += 256) {
        const int row = r0 + i;
        cur[i] = (row < n_nodes) ? offsets[row] : 0;
    }
    __syncthreads();
    const int beg = offsets[r0];
    const int end = offsets[min(r0 + BIN_ROWS, n_nodes)];
    for (int i = beg + t; i < end; i += 256) {
        const uint2 p = tmp8[i];
        const int r = (int)(p.x >> 15);
        const int pos = atomicAdd(&cur[r - r0], 1);
        rec4[pos] = (p.y << 15) | (p.x & 0x7FFFu);
    }
}

// ---------------- per-node reduction + fused tanh ----------------
__global__ __launch_bounds__(256) void gcn_gather_kernel(
        const unsigned int* __restrict__ support_u,
        const unsigned int* __restrict__ rec4,
        const int* __restrict__ offsets,
        float* __restrict__ out, int n_nodes) {
    const int node = __builtin_amdgcn_readfirstlane(
        blockIdx.x * 4 + (threadIdx.x >> 6));
    const int lane = threadIdx.x & 63;
    if (node >= n_nodes) return;

    const int beg = offsets[node];
    const int end = offsets[node + 1];

    float ax = 0.f, ay = 0.f, bx = 0.f, by = 0.f;
    int e = beg;
    for (; e + 3 < end; e += 4) {
        const unsigned r0 = rec4[e + 0];
        const unsigned r1 = rec4[e + 1];
        const unsigned r2 = rec4[e + 2];
        const unsigned r3 = rec4[e + 3];
        const unsigned s0 = support_u[(size_t)(r0 >> 15) * 64 + lane];
        const unsigned s1 = support_u[(size_t)(r1 >> 15) * 64 + lane];
        const unsigned s2 = support_u[(size_t)(r2 >> 15) * 64 + lane];
        const unsigned s3 = support_u[(size_t)(r3 >> 15) * 64 + lane];
        const float v0 = __half2float(__ushort_as_half((unsigned short)(r0 & 0x7FFFu)));
        const float v1 = __half2float(__ushort_as_half((unsigned short)(r1 & 0x7FFFu)));
        const float v2 = __half2float(__ushort_as_half((unsigned short)(r2 & 0x7FFFu)));
        const float v3 = __half2float(__ushort_as_half((unsigned short)(r3 & 0x7FFFu)));
        ax += v0 * __half2float(__ushort_as_half((unsigned short)(s0 & 0xFFFFu)));
        ay += v0 * __half2float(__ushort_as_half((unsigned short)(s0 >> 16)));
        bx += v1 * __half2float(__ushort_as_half((unsigned short)(s1 & 0xFFFFu)));
        by += v1 * __half2float(__ushort_as_half((unsigned short)(s1 >> 16)));
        ax += v2 * __half2float(__ushort_as_half((unsigned short)(s2 & 0xFFFFu)));
        ay += v2 * __half2float(__ushort_as_half((unsigned short)(s2 >> 16)));
        bx += v3 * __half2float(__ushort_as_half((unsigned short)(s3 & 0xFFFFu)));
        by += v3 * __half2float(__ushort_as_half((unsigned short)(s3 >> 16)));
    }
    for (; e < end; ++e) {
        const unsigned r = rec4[e];
        const unsigned s = support_u[(size_t)(r >> 15) * 64 + lane];
        const float v = __half2float(__ushort_as_half((unsigned short)(r & 0x7FFFu)));
        ax += v * __half2float(__ushort_as_half((unsigned short)(s & 0xFFFFu)));
        ay += v * __half2float(__ushort_as_half((unsigned short)(s >> 16)));
    }

    float2* out2 = (float2*)out;
    out2[(size_t)node * 64 + lane] = make_float2(tanhf(ax + bx), tanhf(ay + by));
}

extern "C" void kernel_launch(void* const* d_in, const int* in_sizes, int n_in,
                              void* d_out, int out_size, void* d_ws, size_t ws_size,
                              hipStream_t stream) {
    const float* x    = (const float*)d_in[0];
    const float* W    = (const float*)d_in[1];
    const int*   erow = (const int*)d_in[2];
    const int*   ecol = (const int*)d_in[3];
    const float* eval = (const float*)d_in[4];
    float* out = (float*)d_out;

    const int n_nodes = in_sizes[0] / D;   // 100000
    const int n_edges = in_sizes[2];       // 1600000
    const int nb = (n_nodes + SCAN_BLOCK - 1) / SCAN_BLOCK;       // 391
    const int nbins = (n_nodes + BIN_ROWS - 1) >> BIN_SHIFT;      // 196

    // Workspace layout (16B alignment preserved per chunk)
    unsigned short* support2 = (unsigned short*)d_ws;             // 25.6 MB
    unsigned short* wt = support2 + (size_t)n_nodes * D;          // 32 KB
    uint2* tmp8   = (uint2*)(wt + D * D);                         // 12.8 MB
    unsigned int* rec4 = (unsigned int*)(tmp8 + n_edges);         // 6.4 MB
    int*  counts  = (int*)(rec4 + n_edges);                       // n_nodes
    int*  offsets = counts + n_nodes;                             // n_nodes+1
    int*  bsums   = offsets + n_nodes + 1;                        // nb
    int*  bbase   = bsums + nb;                                   // nb
    int*  ccur    = bbase + nb;                                   // nbins*CPAD

    // 1) wt = f16(W^T); support = fp16(x @ W) via f16 MFMA
    gcn_wt_kernel<<<(D * D) / 256, 256, 0, stream>>>(W, wt);
    gcn_gemm_kernel<<<(n_nodes + 127) / 128, 256, 0, stream>>>(
        x, wt, support2, n_nodes);

    // 2) per-row offsets
    hipMemsetAsync(counts, 0, (size_t)n_nodes * sizeof(int), stream);
    gcn_hist_kernel<<<(n_edges + 255) / 256, 256, 0, stream>>>(erow, counts, n_edges);
    gcn_scanA_kernel<<<nb, SCAN_BLOCK, 0, stream>>>(counts, offsets, bsums, n_nodes);
    gcn_scanB_kernel<<<1, 1024, 0, stream>>>(bsums, bbase, &offsets[n_nodes], nb);
    gcn_scanC_kernel<<<nb, SCAN_BLOCK, 0, stream>>>(offsets, bbase, n_nodes);

    // 3) two-stage binned CSR build
    gcn_ccur_init_kernel<<<(nbins + 255) / 256, 256, 0, stream>>>(offsets, ccur, nbins);
    gcn_binA_kernel<<<(n_edges + AW - 1) / AW, 256, 0, stream>>>(
        erow, ecol, eval, ccur, tmp8, n_edges, nbins);
    gcn_binB_kernel<<<nbins, 256, 0, stream>>>(tmp8, offsets, rec4, n_nodes);

    // 4) per-node reduce + fused tanh
    gcn_gather_kernel<<<(n_nodes + 3) / 4, 256, 0, stream>>>(
        (const unsigned int*)support2, rec4, offsets, out, n_nodes);
}